// Round 14
// baseline (199.922 us; speedup 1.0000x reference)
//
#include <hip/hip_runtime.h>
#include <hip/hip_bf16.h>

// GAT layer, B=4, N=4096, F_in=128, F_out=64.
// out_i = sum_j adj_ij * exp(leaky(s2_i+s1_j)) * Wh_j / sum_j adj_ij*exp(..)
// (softmax normalizer cancels; eps*Z ~2e-9 relative -> dropped; scores O(8)
//  so bare exp2 safe; s1/s2 pre-scaled by log2 e.)
//
// R14 = R9 with K-step 512: each adj row-stream advances in 2KB contiguous
// chunks (vs 1KB) -> half the DRAM page switches; 8 barriers total (vs 16).
// B in two 8-fragment phases (bv[8] reused). VGPR audit ~225 <= 256 (256,2).
// LDS: P [2][32][512] bf16 = 64KB/block, 2 blocks/CU = 128KB.

typedef __attribute__((ext_vector_type(8))) short bf16x8;
typedef __attribute__((ext_vector_type(4))) float f32x4;
typedef __attribute__((ext_vector_type(4))) unsigned int u32x4;

#define LOG2E 1.4426950408889634f

__device__ __forceinline__ unsigned int pk2(float lo, float hi) {
  float2 f2; f2.x = lo; f2.y = hi;
  union { __hip_bfloat162 b; unsigned int u; } c;
  c.b = __float22bfloat162_rn(f2);
  return c.u;
}
__device__ __forceinline__ bf16x8 u2b(u32x4 v) {
  union { u32x4 u; bf16x8 b; } c; c.u = v; return c.b;
}
__device__ __forceinline__ float vexp2_(float x) {
  float r; asm("v_exp_f32 %0, %1" : "=v"(r) : "v"(x)); return r;
}

// ---------------- K1: Wh = h @ W (f32); wt bf16 in fragment order
//   segment S = (b*128 + k/32)*4 + col/16 (1KB); lane ((k%32)/8)*16+col%16
//   holds 8 shorts (k%8). s1 = Wh a1 * log2e, s2 = Wh a2 * log2e.
__global__ __launch_bounds__(256) void k_wh(
    const float* __restrict__ h, const float* __restrict__ W, const float* __restrict__ a,
    unsigned short* __restrict__ wt, float* __restrict__ s1, float* __restrict__ s2) {
  __shared__ float hs[32][130];
  __shared__ float Ws[128 * 64];
  const int t = threadIdx.x;
  const int b = blockIdx.x >> 7;
  const int row0 = (blockIdx.x & 127) << 5;

  #pragma unroll
  for (int it = 0; it < 8; ++it) {
    const int fidx = it * 256 + t;
    ((float4*)Ws)[fidx] = ((const float4*)W)[fidx];
  }
  #pragma unroll
  for (int it = 0; it < 4; ++it) {
    int flat = it * 256 + t;
    int r = flat >> 5, q = flat & 31;
    const float4 v = *(const float4*)(h + ((size_t)(b * 4096 + row0 + r)) * 128 + 4 * q);
    hs[r][4*q+0] = v.x; hs[r][4*q+1] = v.y; hs[r][4*q+2] = v.z; hs[r][4*q+3] = v.w;
  }
  __syncthreads();

  const int rg = t >> 4, cg = t & 15;
  float acc[2][4] = {};
  for (int k = 0; k < 128; ++k) {
    float4 wv = ((const float4*)Ws)[k * 16 + cg];
    #pragma unroll
    for (int i = 0; i < 2; ++i) {
      float hv = hs[2*rg + i][k];
      acc[i][0] = fmaf(hv, wv.x, acc[i][0]);
      acc[i][1] = fmaf(hv, wv.y, acc[i][1]);
      acc[i][2] = fmaf(hv, wv.z, acc[i][2]);
      acc[i][3] = fmaf(hv, wv.w, acc[i][3]);
    }
  }
  __syncthreads();

  float (*WhF)[68] = (float(*)[68])hs;
  #pragma unroll
  for (int i = 0; i < 2; ++i)
    #pragma unroll
    for (int j = 0; j < 4; ++j)
      WhF[2*rg + i][4*cg + j] = acc[i][j];
  __syncthreads();

  if (t < 32) {
    float x1 = 0.f, x2 = 0.f;
    #pragma unroll 8
    for (int c = 0; c < 64; ++c) {
      float v = WhF[t][c];
      x1 = fmaf(v, a[c], x1);
      x2 = fmaf(v, a[64 + c], x2);
    }
    s1[b * 4096 + row0 + t] = x1 * LOG2E;
    s2[b * 4096 + row0 + t] = x2 * LOG2E;
  }

  const int col = t >> 2, sub = t & 3;
  unsigned int uh[4];
  #pragma unroll
  for (int r = 0; r < 4; ++r)
    uh[r] = pk2(WhF[8*sub + 2*r][col], WhF[8*sub + 2*r + 1][col]);
  const int S = (b * 128 + (row0 >> 5)) * 4 + (col >> 4);
  unsigned short* dst = wt + ((size_t)S << 9) + sub * 128 + (col & 15) * 8;
  *(uint4*)dst = make_uint4(uh[0], uh[1], uh[2], uh[3]);
}

// ---------------- K3: out = P @ Wh, K-step 512 (8 steps, 1 barrier each).
// 512 blocks x 256 thr, 2 blocks/CU. Wave w: adj rows 8w..8w+7, each read as
// 2KB contiguous per step; output cols 16w..16w+16, fragment-order B in two
// 8-frag phases. P: regs -> XOR-swizzled LDS ([32][512] bf16) -> A-frags.
__global__ __launch_bounds__(256, 2) void k_main(
    const float* __restrict__ adj, const unsigned short* __restrict__ wt,
    const float* __restrict__ s1, const float* __restrict__ s2,
    float* __restrict__ out) {
  __shared__ unsigned short Pws[2][32 * 512];   // 2 x 32KB, XOR-swizzled rows
  __shared__ float Ss[32];

  const int t = threadIdx.x;
  const int blk = blockIdx.x;
  const int xcd = blk & 7;                   // default round-robin XCD id
  const int b = xcd >> 1;                    // one batch per XCD pair
  const int tile = (blk >> 3) + ((xcd & 1) << 6);   // 0..127 bijective per b
  const int row0 = tile << 5;
  const int l = t & 63, w = t >> 6;
  const int lr = l & 15, g = l >> 4;

  const float* adjW = adj + ((size_t)(b * 4096 + row0 + 8 * w)) * 4096 + 4 * l;
  const float* s1W  = s1 + b * 4096 + 4 * l;
  const unsigned short* wtW = wt + (((size_t)b * 512 + w) << 9) + 8 * l;

  float s2r[8];
  #pragma unroll
  for (int r = 0; r < 8; ++r) s2r[r] = s2[b * 4096 + row0 + 8 * w + r];

  float sar[8] = {0.f,0.f,0.f,0.f,0.f,0.f,0.f,0.f};
  f32x4 acc0 = {0.f,0.f,0.f,0.f}, acc1 = {0.f,0.f,0.f,0.f};

  f32x4 aX[8][2], aY[8][2], sX[2], sY[2];
  u32x4 bv[8];

  // per row: lane l covers cols [4l,4l+4) and [256+4l,256+4l+4)
#define LOADADJ(av, sv, ks) do {                                              \
    const int ko = ((ks) & 7) << 9;                                           \
    _Pragma("unroll")                                                         \
    for (int r = 0; r < 8; ++r) {                                             \
      av[r][0] = *(const f32x4*)(adjW + (size_t)r * 4096 + ko);               \
      av[r][1] = *(const f32x4*)(adjW + (size_t)r * 4096 + ko + 256);         \
    }                                                                         \
    sv[0] = *(const f32x4*)(s1W + ko);                                        \
    sv[1] = *(const f32x4*)(s1W + ko + 256);                                  \
  } while (0)

  // 8 contiguous 1KB fragment loads: k32 = ks*16 + ph*8 + kk
#define LOADBH(ks, ph) do {                                                   \
    _Pragma("unroll")                                                         \
    for (int kk = 0; kk < 8; ++kk)                                            \
      bv[kk] = *(const u32x4*)(wtW + (size_t)((ks) * 16 + (ph) * 8 + kk) * 2048); \
  } while (0)

  // swizzle: col c of local row rl lives at short-offset c ^ ((rl&7)<<3)
#define PBUILD(av, sv, buf) do {                                              \
    unsigned short* Pd = &Pws[buf][0];                                        \
    _Pragma("unroll")                                                         \
    for (int r = 0; r < 8; ++r) {                                             \
      const int rl = 8 * w + r;                                               \
      const int sw = (rl & 7) << 3;                                           \
      _Pragma("unroll")                                                       \
      for (int hh = 0; hh < 2; ++hh) {                                        \
        float e0 = s2r[r] + sv[hh][0], e1 = s2r[r] + sv[hh][1];               \
        float e2 = s2r[r] + sv[hh][2], e3 = s2r[r] + sv[hh][3];               \
        e0 = fmaxf(e0, 0.2f * e0); e1 = fmaxf(e1, 0.2f * e1);                 \
        e2 = fmaxf(e2, 0.2f * e2); e3 = fmaxf(e3, 0.2f * e3);                 \
        float p0 = vexp2_(e0), p1 = vexp2_(e1);                               \
        float p2 = vexp2_(e2), p3 = vexp2_(e3);                               \
        float w0 = av[r][hh][0] * p0, w1 = av[r][hh][1] * p1;                 \
        float w2 = av[r][hh][2] * p2, w3 = av[r][hh][3] * p3;                 \
        sar[r] += (w0 + w1) + (w2 + w3);                                      \
        uint2 pk; pk.x = pk2(w0, w1); pk.y = pk2(w2, w3);                     \
        *(uint2*)(Pd + rl * 512 + ((256 * hh + 4 * l) ^ sw)) = pk;            \
      }                                                                       \
    }                                                                         \
  } while (0)

#define SYNC() do {                                                           \
    asm volatile("s_waitcnt lgkmcnt(0)" ::: "memory");                        \
    __builtin_amdgcn_sched_barrier(0);                                        \
    __builtin_amdgcn_s_barrier();                                             \
    __builtin_amdgcn_sched_barrier(0);                                        \
  } while (0)

#define MFMAH(buf, ph) do {                                                   \
    const unsigned short* Pr = &Pws[buf][0];                                  \
    _Pragma("unroll")                                                         \
    for (int kk = 0; kk < 8; ++kk) {                                          \
      const int koff = (8 * g + 32 * ((ph) * 8 + kk)) ^ ((lr & 7) << 3);      \
      bf16x8 a0 = *(const bf16x8*)(Pr + lr * 512 + koff);                     \
      bf16x8 a1 = *(const bf16x8*)(Pr + (16 + lr) * 512 + koff);              \
      acc0 = __builtin_amdgcn_mfma_f32_16x16x32_bf16(a0, u2b(bv[kk]), acc0, 0, 0, 0); \
      acc1 = __builtin_amdgcn_mfma_f32_16x16x32_bf16(a1, u2b(bv[kk]), acc1, 0, 0, 0); \
    }                                                                         \
  } while (0)

#define STEP(av, sv, buf, s) do {                                             \
    LOADBH(s, 0);                    /* B half0, lands during PBUILD+SYNC */  \
    PBUILD(av, sv, buf);                                                      \
    LOADADJ(av, sv, (s) + 2);        /* depth-2 HBM prefetch (wraps) */       \
    SYNC();                          /* lgkm only: prefetch stays in flight */\
    MFMAH(buf, 0);                                                            \
    LOADBH(s, 1);                    /* B half1, covered by half0 MFMAs */    \
    MFMAH(buf, 1);                                                            \
  } while (0)

  LOADADJ(aX, sX, 0);
  LOADADJ(aY, sY, 1);

  for (int it = 0; it < 4; ++it) {
    STEP(aX, sX, 0, 2 * it);
    STEP(aY, sY, 1, 2 * it + 1);
  }

  // S row sums: full-wave butterfly per row, lane 0 publishes
  #pragma unroll
  for (int r = 0; r < 8; ++r) {
    float v = sar[r];
    #pragma unroll
    for (int m = 1; m < 64; m <<= 1) v += __shfl_xor(v, m);
    sar[r] = v;
  }
  if (l == 0) {
    #pragma unroll
    for (int r = 0; r < 8; ++r) Ss[8 * w + r] = sar[r];
  }
  __syncthreads();

  // epilogue: C layout col=lr, row=4g+reg (+16 for acc1); out col = 16w+lr
  #pragma unroll
  for (int reg = 0; reg < 4; ++reg) {
    const int r0 = 4 * g + reg, r1 = 16 + 4 * g + reg;
    const float i0 = 1.0f / Ss[r0], i1 = 1.0f / Ss[r1];
    const size_t ob = ((size_t)(b * 4096 + row0 + r0)) * 64 + 16 * w + lr;
    out[ob] = acc0[reg] * i0;
    out[ob + (size_t)16 * 64] = acc1[reg] * i1;
  }
}

extern "C" void kernel_launch(void* const* d_in, const int* in_sizes, int n_in,
                              void* d_out, int out_size, void* d_ws, size_t ws_size,
                              hipStream_t stream) {
  const float* h   = (const float*)d_in[0];
  const float* adj = (const float*)d_in[1];
  const float* W   = (const float*)d_in[2];
  const float* a   = (const float*)d_in[3];
  float* out = (float*)d_out;

  // ws layout: wt (2MB bf16, fragment order) | s1 (64KB) | s2 (64KB)
  unsigned short* wt = (unsigned short*)d_ws;
  float* s1 = (float*)(wt + (size_t)4 * 64 * 4096);
  float* s2 = s1 + 16384;

  k_wh  <<<512, 256, 0, stream>>>(h, W, a, wt, s1, s2);
  k_main<<<512, 256, 0, stream>>>(adj, wt, s1, s2, out);
}

// Round 15
// 61.565 us; speedup vs baseline: 3.2473x; 3.2473x over previous
//
#include <hip/hip_runtime.h>
#include <hip/hip_bf16.h>

// GAT layer, B=4, N=4096, F_in=128, F_out=64.
// out_i = sum_j adj_ij * exp(leaky(s2_i+s1_j)) * Wh_j / sum_j adj_ij*exp(..)
// (softmax normalizer cancels; eps*Z term is 2e-9 relative -> dropped;
//  scores O(8) so bare exp2 is safe; s1/s2 pre-scaled by log2 e.)
//
// R15 = R9 verbatim (session best, 60.3us). Evidence summary:
//  - fragment-order B (R9): 16 txns/KB, the decisive L1-transaction fix (+14%)
//  - 1KB-contiguous adj row chunks (R7): +16%
//  - plain (non-nt) adj loads + LDS-staged W in k_wh (R8): +9%
//  - occupancy 2->4 blocks/CU (R13), barrier-free (R12): flat -> not the wall
//  - K-step 512 / 16-row tiles / (256,3): spill or 2x B traffic -> regress
// Remaining ~25% over the 43us adj floor attributed to mixed-stream DRAM
// efficiency (32 row-streams/CU + B stream) — no HIP-level lever found.

typedef __attribute__((ext_vector_type(8))) short bf16x8;
typedef __attribute__((ext_vector_type(4))) float f32x4;
typedef __attribute__((ext_vector_type(4))) unsigned int u32x4;

#define LOG2E 1.4426950408889634f

__device__ __forceinline__ unsigned int pk2(float lo, float hi) {
  float2 f2; f2.x = lo; f2.y = hi;
  union { __hip_bfloat162 b; unsigned int u; } c;
  c.b = __float22bfloat162_rn(f2);
  return c.u;
}
__device__ __forceinline__ bf16x8 u2b(u32x4 v) {
  union { u32x4 u; bf16x8 b; } c; c.u = v; return c.b;
}
__device__ __forceinline__ float vexp2_(float x) {
  float r; asm("v_exp_f32 %0, %1" : "=v"(r) : "v"(x)); return r;
}

// ---------------- K1: Wh = h @ W (f32); wt bf16 in fragment order
//   segment S = (b*128 + k/32)*4 + col/16 (1KB); lane ((k%32)/8)*16+col%16
//   holds 8 shorts (k%8). s1 = Wh a1 * log2e, s2 = Wh a2 * log2e.
__global__ __launch_bounds__(256) void k_wh(
    const float* __restrict__ h, const float* __restrict__ W, const float* __restrict__ a,
    unsigned short* __restrict__ wt, float* __restrict__ s1, float* __restrict__ s2) {
  __shared__ float hs[32][130];
  __shared__ float Ws[128 * 64];
  const int t = threadIdx.x;
  const int b = blockIdx.x >> 7;
  const int row0 = (blockIdx.x & 127) << 5;

  // stage W (32KB) into LDS, once
  #pragma unroll
  for (int it = 0; it < 8; ++it) {
    const int fidx = it * 256 + t;
    ((float4*)Ws)[fidx] = ((const float4*)W)[fidx];
  }
  // stage h tile: 32 rows x 128 f32
  #pragma unroll
  for (int it = 0; it < 4; ++it) {
    int flat = it * 256 + t;
    int r = flat >> 5, q = flat & 31;
    const float4 v = *(const float4*)(h + ((size_t)(b * 4096 + row0 + r)) * 128 + 4 * q);
    hs[r][4*q+0] = v.x; hs[r][4*q+1] = v.y; hs[r][4*q+2] = v.z; hs[r][4*q+3] = v.w;
  }
  __syncthreads();

  const int rg = t >> 4, cg = t & 15;
  float acc[2][4] = {};
  for (int k = 0; k < 128; ++k) {
    float4 wv = ((const float4*)Ws)[k * 16 + cg];   // LDS b128, 2-way max
    #pragma unroll
    for (int i = 0; i < 2; ++i) {
      float hv = hs[2*rg + i][k];
      acc[i][0] = fmaf(hv, wv.x, acc[i][0]);
      acc[i][1] = fmaf(hv, wv.y, acc[i][1]);
      acc[i][2] = fmaf(hv, wv.z, acc[i][2]);
      acc[i][3] = fmaf(hv, wv.w, acc[i][3]);
    }
  }
  __syncthreads();

  float (*WhF)[68] = (float(*)[68])hs;
  #pragma unroll
  for (int i = 0; i < 2; ++i)
    #pragma unroll
    for (int j = 0; j < 4; ++j)
      WhF[2*rg + i][4*cg + j] = acc[i][j];
  __syncthreads();

  if (t < 32) {
    float x1 = 0.f, x2 = 0.f;
    #pragma unroll 8
    for (int c = 0; c < 64; ++c) {
      float v = WhF[t][c];
      x1 = fmaf(v, a[c], x1);
      x2 = fmaf(v, a[64 + c], x2);
    }
    s1[b * 4096 + row0 + t] = x1 * LOG2E;
    s2[b * 4096 + row0 + t] = x2 * LOG2E;
  }

  // fragment-order store: this tile covers kk32 = row0>>5 exactly.
  const int col = t >> 2, sub = t & 3;   // sub = (k%32)/8
  unsigned int uh[4];
  #pragma unroll
  for (int r = 0; r < 4; ++r)
    uh[r] = pk2(WhF[8*sub + 2*r][col], WhF[8*sub + 2*r + 1][col]);
  const int S = (b * 128 + (row0 >> 5)) * 4 + (col >> 4);
  unsigned short* dst = wt + ((size_t)S << 9) + sub * 128 + (col & 15) * 8;
  *(uint4*)dst = make_uint4(uh[0], uh[1], uh[2], uh[3]);
}

// ---------------- K3: out = P @ Wh, K-step 256.
// 512 blocks x 256 thr (4 waves, 2 blocks/CU). Wave w owns adj rows 8w..8w+7
// (1KB-contiguous loads) and output cols 16w..16w+16 (B private, contiguous
// 1KB fragment loads). P: registers -> swizzled LDS -> A-frags.
__global__ __launch_bounds__(256, 2) void k_main(
    const float* __restrict__ adj, const unsigned short* __restrict__ wt,
    const float* __restrict__ s1, const float* __restrict__ s2,
    float* __restrict__ out) {
  __shared__ unsigned short Pws[2][8192];   // 2 x (32 rows x 512B, XOR-swizzled)
  __shared__ float Ss[32];

  const int t = threadIdx.x;
  const int blk = blockIdx.x;
  const int xcd = blk & 7;                   // default round-robin XCD id
  const int b = xcd >> 1;                    // one batch per XCD pair: wt L2-resident
  const int tile = (blk >> 3) + ((xcd & 1) << 6);   // 0..127 bijective per b
  const int row0 = tile << 5;
  const int l = t & 63, w = t >> 6;
  const int lr = l & 15, g = l >> 4;

  const float* adjW = adj + ((size_t)(b * 4096 + row0 + 8 * w)) * 4096 + 4 * l;
  const float* s1W  = s1 + b * 4096 + 4 * l;
  // fragment-order B base for this wave: segment (b*128 + kk32)*4 + w
  const unsigned short* wtW = wt + (((size_t)(b * 128) * 4 + w) << 9) + 8 * l;

  float s2r[8];
  #pragma unroll
  for (int r = 0; r < 8; ++r) s2r[r] = s2[b * 4096 + row0 + 8 * w + r];

  float sar[8] = {0.f,0.f,0.f,0.f,0.f,0.f,0.f,0.f};
  f32x4 acc0 = {0.f,0.f,0.f,0.f}, acc1 = {0.f,0.f,0.f,0.f};

  f32x4 aX[8], aY[8], sX, sY;
  u32x4 bv[8];

#define LOADADJ(av, sv, ks) do {                                              \
    const int ko = ((ks) & 15) << 8;                                          \
    _Pragma("unroll")                                                         \
    for (int r = 0; r < 8; ++r)                                               \
      av[r] = *(const f32x4*)(adjW + (size_t)r * 4096 + ko);                  \
    sv = *(const f32x4*)(s1W + ko);                                           \
  } while (0)

  // 8 contiguous 1KB loads: kk32 = ksm*8 + kk, stride 4 segments (2048 shorts)
#define LOADB(ks) do {                                                        \
    const int ksm = (ks) & 15;                                                \
    const unsigned short* bp = wtW + ((size_t)(ksm * 8) << 11);               \
    _Pragma("unroll")                                                         \
    for (int kk = 0; kk < 8; ++kk)                                            \
      bv[kk] = *(const u32x4*)(bp + (kk << 11));                              \
  } while (0)

  // lane l holds rows 8w..8w+7, cols [4l,4l+4). Write 8B to swizzled P row:
  // element col c of row r8 lives at short-offset c ^ ((r8&7)<<3).
#define PBUILD(av, sv, buf) do {                                              \
    unsigned short* Pd = &Pws[buf][0];                                        \
    _Pragma("unroll")                                                         \
    for (int r = 0; r < 8; ++r) {                                             \
      float e0 = s2r[r] + sv[0], e1 = s2r[r] + sv[1];                         \
      float e2 = s2r[r] + sv[2], e3 = s2r[r] + sv[3];                         \
      e0 = fmaxf(e0, 0.2f * e0); e1 = fmaxf(e1, 0.2f * e1);                   \
      e2 = fmaxf(e2, 0.2f * e2); e3 = fmaxf(e3, 0.2f * e3);                   \
      float p0 = vexp2_(e0), p1 = vexp2_(e1);                                 \
      float p2 = vexp2_(e2), p3 = vexp2_(e3);                                 \
      float w0 = av[r][0] * p0, w1 = av[r][1] * p1;                           \
      float w2 = av[r][2] * p2, w3 = av[r][3] * p3;                           \
      sar[r] += (w0 + w1) + (w2 + w3);                                        \
      uint2 pk; pk.x = pk2(w0, w1); pk.y = pk2(w2, w3);                       \
      *(uint2*)(Pd + (8 * w + r) * 256 + ((4 * l) ^ (r << 3))) = pk;          \
    }                                                                         \
  } while (0)

#define SYNC() do {                                                           \
    asm volatile("s_waitcnt lgkmcnt(0)" ::: "memory");                        \
    __builtin_amdgcn_sched_barrier(0);                                        \
    __builtin_amdgcn_s_barrier();                                             \
    __builtin_amdgcn_sched_barrier(0);                                        \
  } while (0)

#define MFMAP(buf) do {                                                       \
    const unsigned short* Pr = &Pws[buf][0];                                  \
    _Pragma("unroll")                                                         \
    for (int kk = 0; kk < 8; ++kk) {                                          \
      const int koff = (8 * g + 32 * kk) ^ ((lr & 7) << 3);                   \
      bf16x8 a0 = *(const bf16x8*)(Pr + lr * 256 + koff);                     \
      bf16x8 a1 = *(const bf16x8*)(Pr + (16 + lr) * 256 + koff);              \
      acc0 = __builtin_amdgcn_mfma_f32_16x16x32_bf16(a0, u2b(bv[kk]), acc0, 0, 0, 0); \
      acc1 = __builtin_amdgcn_mfma_f32_16x16x32_bf16(a1, u2b(bv[kk]), acc1, 0, 0, 0); \
    }                                                                         \
  } while (0)

  LOADADJ(aX, sX, 0);
  LOADADJ(aY, sY, 1);
  LOADB(0);

  for (int it = 0; it < 8; ++it) {
    PBUILD(aX, sX, 0);
    LOADADJ(aX, sX, 2 * it + 2);   // depth-2 HBM prefetch (wraps harmlessly)
    SYNC();                        // lgkm only: HBM prefetch stays in flight
    MFMAP(0);
    LOADB(2 * it + 1);             // B(s+1): in flight across next P-build

    PBUILD(aY, sY, 1);
    LOADADJ(aY, sY, 2 * it + 3);
    SYNC();
    MFMAP(1);
    LOADB(2 * it + 2);
  }

  // S row sums: full-wave butterfly per row, lane 0 publishes
  #pragma unroll
  for (int r = 0; r < 8; ++r) {
    float v = sar[r];
    #pragma unroll
    for (int m = 1; m < 64; m <<= 1) v += __shfl_xor(v, m);
    sar[r] = v;
  }
  if (l == 0) {
    #pragma unroll
    for (int r = 0; r < 8; ++r) Ss[8 * w + r] = sar[r];
  }
  __syncthreads();

  // epilogue: out = acc / S ; C layout col=lr, row=4g+reg (+16 for acc1)
  #pragma unroll
  for (int reg = 0; reg < 4; ++reg) {
    const int r0 = 4 * g + reg, r1 = 16 + 4 * g + reg;
    const float i0 = 1.0f / Ss[r0], i1 = 1.0f / Ss[r1];
    const size_t ob = ((size_t)(b * 4096 + row0 + r0)) * 64 + 16 * w + lr;
    out[ob] = acc0[reg] * i0;
    out[ob + (size_t)16 * 64] = acc1[reg] * i1;
  }
}

extern "C" void kernel_launch(void* const* d_in, const int* in_sizes, int n_in,
                              void* d_out, int out_size, void* d_ws, size_t ws_size,
                              hipStream_t stream) {
  const float* h   = (const float*)d_in[0];
  const float* adj = (const float*)d_in[1];
  const float* W   = (const float*)d_in[2];
  const float* a   = (const float*)d_in[3];
  float* out = (float*)d_out;

  // ws layout: wt (2MB bf16, fragment order) | s1 (64KB) | s2 (64KB)
  unsigned short* wt = (unsigned short*)d_ws;
  float* s1 = (float*)(wt + (size_t)4 * 64 * 4096);
  float* s2 = s1 + 16384;

  k_wh  <<<512, 256, 0, stream>>>(h, W, a, wt, s1, s2);
  k_main<<<512, 256, 0, stream>>>(adj, wt, s1, s2, out);
}